// Round 3
// baseline (998.997 us; speedup 1.0000x reference)
//
#include <hip/hip_runtime.h>
#include <hip/hip_bf16.h>

typedef __bf16 bf16_t;
typedef __bf16 bf16x8 __attribute__((ext_vector_type(8)));
typedef float floatx4 __attribute__((ext_vector_type(4)));

#define NB 2
#define NT 2048
#define NC 1024
#define NH 16
#define HD 64
#define BT (NB*NT)

// Q prescale: 0.125 (1/sqrt(64)) * log2(e), so attn logits come out in exp2 domain
#define ASCALE 0.1803368801111204f

__device__ __forceinline__ void gload16(const bf16_t* g, bf16_t* l){
  __builtin_amdgcn_global_load_lds((const __attribute__((address_space(1))) void*)g,
                                   (__attribute__((address_space(3))) void*)l, 16, 0, 0);
}

// ---------------- convert x: fp32 -> bf16 ----------------
__global__ void k_cvt_x(const float* __restrict__ x, bf16_t* __restrict__ xb, int n){
  int i = (blockIdx.x*blockDim.x + threadIdx.x)*4;
  if (i >= n) return;
  float4 v = *(const float4*)(x+i);
  bf16_t o[4] = {(bf16_t)v.x,(bf16_t)v.y,(bf16_t)v.z,(bf16_t)v.w};
  *(uint2*)(xb+i) = *(const uint2*)o;
}

// ------- transpose-convert: in fp32 [K][N] -> out bf16 [N][K] -------
__global__ void k_cvt_t(const float* __restrict__ in, bf16_t* __restrict__ out, int K, int N){
  __shared__ float tile[32][33];
  int tid = threadIdx.x;
  int kt = blockIdx.y*32, nt = blockIdx.x*32;
  int row = tid>>3, c4 = (tid&7)*4;
  float4 v = *(const float4*)(in + (size_t)(kt+row)*N + nt + c4);
  tile[row][c4+0]=v.x; tile[row][c4+1]=v.y; tile[row][c4+2]=v.z; tile[row][c4+3]=v.w;
  __syncthreads();
  bf16_t o[4];
  #pragma unroll
  for (int i=0;i<4;i++) o[i] = (bf16_t)tile[c4+i][row];
  *(uint2*)(out + (size_t)(nt+row)*K + kt + c4) = *(const uint2*)o;
}

// ------- m97-style GEMM: C[M][N] = A[M][K] * Bt[N][K]^T, 128x128 tile, BK=32 -------
// global_load_lds width-16 staging; 4 waves, each 64x64 (4x4 MFMA 16x16x32)
template<bool BIAS, bool OUTBF>
__global__ __launch_bounds__(256) void k_gemm(
    const bf16_t* __restrict__ A, const bf16_t* __restrict__ Bt,
    void* __restrict__ Cv, const float* __restrict__ bias, int M, int N, int K){
  __shared__ __align__(16) bf16_t As[128*32];
  __shared__ __align__(16) bf16_t Bs[128*32];
  int tid = threadIdx.x;
  int wave = tid>>6, lane = tid&63, quad = lane>>4, l15 = lane&15;
  int m0 = blockIdx.y*128, n0 = blockIdx.x*128;
  int wm = (wave>>1)*64, wn = (wave&1)*64;
  floatx4 acc[4][4];
  #pragma unroll
  for(int i=0;i<4;i++)
    #pragma unroll
    for(int j=0;j<4;j++) acc[i][j] = (floatx4){0.f,0.f,0.f,0.f};
  // staging map: linear chunk l = i*256+tid -> row l>>2, 16B chunk l&3; LDS offset = l*16B
  int r0 = tid>>2, ch8 = (tid&3)*8;
  const bf16_t* Ag0 = A  + (size_t)(m0+r0)*K    + ch8;
  const bf16_t* Ag1 = A  + (size_t)(m0+r0+64)*K + ch8;
  const bf16_t* Bg0 = Bt + (size_t)(n0+r0)*K    + ch8;
  const bf16_t* Bg1 = Bt + (size_t)(n0+r0+64)*K + ch8;
  bf16_t* Al0 = As + (size_t)tid*8;
  bf16_t* Al1 = As + (size_t)(256+tid)*8;
  bf16_t* Bl0 = Bs + (size_t)tid*8;
  bf16_t* Bl1 = Bs + (size_t)(256+tid)*8;
  for (int k0=0;k0<K;k0+=32){
    gload16(Ag0+k0, Al0);
    gload16(Ag1+k0, Al1);
    gload16(Bg0+k0, Bl0);
    gload16(Bg1+k0, Bl1);
    __syncthreads();
    bf16x8 af[4], bfr[4];
    #pragma unroll
    for(int mi=0;mi<4;mi++) af[mi]  = *(const bf16x8*)&As[(wm+mi*16+l15)*32 + quad*8];
    #pragma unroll
    for(int ni=0;ni<4;ni++) bfr[ni] = *(const bf16x8*)&Bs[(wn+ni*16+l15)*32 + quad*8];
    #pragma unroll
    for(int mi=0;mi<4;mi++)
      #pragma unroll
      for(int ni=0;ni<4;ni++)
        acc[mi][ni] = __builtin_amdgcn_mfma_f32_16x16x32_bf16(af[mi], bfr[ni], acc[mi][ni],0,0,0);
    __syncthreads();
  }
  #pragma unroll
  for(int ni=0;ni<4;ni++){
    int col = n0 + wn + ni*16 + l15;
    float bv = 0.f; if (BIAS) bv = bias[col];
    #pragma unroll
    for(int mi=0;mi<4;mi++){
      int rowb = m0 + wm + mi*16 + quad*4;
      #pragma unroll
      for(int r=0;r<4;r++){
        float v = acc[mi][ni][r] + bv;
        if (OUTBF) ((bf16_t*)Cv)[(size_t)(rowb+r)*N + col] = (bf16_t)v;
        else       ((float*)Cv)[(size_t)(rowb+r)*N + col]  = v;
      }
    }
  }
}

// ------- RoPE + head split. Q prescaled by ASCALE; V written TRANSPOSED [bh][d][t] -------
__global__ void k_rope(const bf16_t* __restrict__ qkv, bf16_t* __restrict__ Qb,
                       bf16_t* __restrict__ Kb, bf16_t* __restrict__ VT){
  int p = blockIdx.x*blockDim.x + threadIdx.x;     // pair index
  int r = p / 1536;
  int c = (p - r*1536)*2;
  int s = c >> 10, rem = c & 1023;
  int h = rem >> 6, d = rem & 63, j = d >> 1;
  int b = r >> 11, t = r & 2047;
  float x1 = (float)qkv[(size_t)r*3072 + c];
  float x2 = (float)qkv[(size_t)r*3072 + c + 1];
  if (s < 2){
    float freq = exp2f(-0.8304820237218406f * (float)(j & 15));
    float ang = (float)t * freq;
    float sn, cs;
    sincosf(ang, &sn, &cs);
    float o1 = x1*cs - x2*sn;
    float o2 = x2*cs + x1*sn;
    if (s == 0){ o1 *= ASCALE; o2 *= ASCALE; }
    bf16_t* dst = (s==0) ? Qb : Kb;
    bf16_t o[2] = {(bf16_t)o1, (bf16_t)o2};
    *(unsigned int*)(dst + (size_t)((b*NH + h)*NT + t)*HD + d) = *(const unsigned int*)o;
  } else {
    size_t base = ((size_t)(b*NH + h)*HD + d)*NT + t;
    VT[base]      = (bf16_t)x1;
    VT[base + NT] = (bf16_t)x2;
  }
}

// ------- fused attention, ZERO barriers: direct-global K/V^T fragments, wave-private P LDS -------
// grid (bh, qt): all q-tiles of one head land on one XCD (linear%8 heuristic) for L2 K/V locality
__global__ __launch_bounds__(256) void k_attn(
    const bf16_t* __restrict__ Qb, const bf16_t* __restrict__ Kb, const bf16_t* __restrict__ VT,
    float* __restrict__ attn, bf16_t* __restrict__ Ob){
  __shared__ __align__(16) bf16_t Ps[4][16][40];  // per-wave P transpose buffer (wave-private)
  int tid = threadIdx.x;
  int wave = tid>>6, lane = tid&63, quad = lane>>4, l15 = lane&15;
  int bh = blockIdx.x, qt = blockIdx.y;
  int h = bh & (NH-1);
  float slopeL = 1.44269504f * exp2f(-0.5f*(float)(h+1));   // ALiBi slope * log2(e)
  int qbase = qt*64 + wave*16;
  const bf16_t* qrow = Qb + ((size_t)bh*NT + qbase + l15)*HD;
  bf16x8 qa0 = *(const bf16x8*)(qrow + quad*8);
  bf16x8 qa1 = *(const bf16x8*)(qrow + 32 + quad*8);
  const bf16_t* kb_base = Kb + ((size_t)bh*NT + l15)*HD + quad*8;   // + kpos*HD
  const bf16_t* vt_base = VT + ((size_t)bh*HD + l15)*NT + quad*8;   // + dt*16*NT + k0
  const floatx4 z4 = {0.f,0.f,0.f,0.f};
  float qf[4];
  #pragma unroll
  for (int r=0;r<4;r++) qf[r] = (float)(qbase + quad*4 + r);

  // ---- pass 1: row sums of 2^s (diag logit >= 0 -> stable without max) ----
  float lsum[4] = {0.f,0.f,0.f,0.f};
  #pragma unroll 4
  for (int k16=0;k16<NT;k16+=16){
    bf16x8 kb0 = *(const bf16x8*)(kb_base + (size_t)k16*HD);
    bf16x8 kb1 = *(const bf16x8*)(kb_base + (size_t)k16*HD + 32);
    floatx4 sv = __builtin_amdgcn_mfma_f32_16x16x32_bf16(qa0, kb0, z4,0,0,0);
    sv = __builtin_amdgcn_mfma_f32_16x16x32_bf16(qa1, kb1, sv,0,0,0);
    float kf = (float)(k16 + l15);
    #pragma unroll
    for (int r=0;r<4;r++)
      lsum[r] += exp2f(__builtin_fmaf(-slopeL, fabsf(qf[r]-kf), sv[r]));
  }
  #pragma unroll
  for (int r=0;r<4;r++){
    #pragma unroll
    for (int off=1;off<16;off<<=1) lsum[r] += __shfl_xor(lsum[r], off, 16);
  }
  float invl[4];
  #pragma unroll
  for (int r=0;r<4;r++) invl[r] = 1.f / lsum[r];

  // ---- pass 2: recompute S, write normalized attn, O += P V (no barriers) ----
  floatx4 oacc[4] = {z4,z4,z4,z4};
  float* attnrow = attn + (size_t)bh*NT*NT;
  #pragma unroll 2
  for (int k0=0;k0<NT;k0+=32){
    #pragma unroll
    for (int nt=0;nt<2;nt++){
      int k16 = k0 + nt*16;
      bf16x8 kb0 = *(const bf16x8*)(kb_base + (size_t)k16*HD);
      bf16x8 kb1 = *(const bf16x8*)(kb_base + (size_t)k16*HD + 32);
      floatx4 sv = __builtin_amdgcn_mfma_f32_16x16x32_bf16(qa0, kb0, z4,0,0,0);
      sv = __builtin_amdgcn_mfma_f32_16x16x32_bf16(qa1, kb1, sv,0,0,0);
      float kf = (float)(k16 + l15);
      int kpos = k16 + l15;
      #pragma unroll
      for (int r=0;r<4;r++){
        float pv = exp2f(__builtin_fmaf(-slopeL, fabsf(qf[r]-kf), sv[r])) * invl[r];
        attnrow[(size_t)(qbase + quad*4 + r)*NT + kpos] = pv;   // normalized attn
        Ps[wave][quad*4+r][nt*16+l15] = (bf16_t)pv;             // D-layout -> LDS
      }
    }
    // wave-private LDS: in-wave lgkmcnt ordering suffices, no barrier
    bf16x8 pa = *(const bf16x8*)&Ps[wave][l15][quad*8];         // A-layout (16q x 32k)
    #pragma unroll
    for (int dt=0;dt<4;dt++){
      bf16x8 vb = *(const bf16x8*)(vt_base + (size_t)dt*16*NT + k0);
      oacc[dt] = __builtin_amdgcn_mfma_f32_16x16x32_bf16(pa, vb, oacc[dt],0,0,0);
    }
  }
  int b = bh >> 4;
  #pragma unroll
  for (int dt=0;dt<4;dt++){
    #pragma unroll
    for (int r=0;r<4;r++){
      int t = qbase + quad*4 + r;
      Ob[(size_t)(b*NT + t)*NC + h*HD + dt*16 + l15] = (bf16_t)oacc[dt][r];
    }
  }
}

extern "C" void kernel_launch(void* const* d_in, const int* in_sizes, int n_in,
                              void* d_out, int out_size, void* d_ws, size_t ws_size,
                              hipStream_t stream){
  const float* x    = (const float*)d_in[0];
  const float* Wqkv = (const float*)d_in[1];
  const float* Wout = (const float*)d_in[2];
  const float* bout = (const float*)d_in[3];
  (void)in_sizes; (void)n_in; (void)out_size; (void)ws_size;

  char* ws = (char*)d_ws;
  size_t off = 0;
  auto alloc = [&](size_t elems)->bf16_t* {
    bf16_t* p = (bf16_t*)(ws + off);
    off += ((elems*sizeof(bf16_t) + 255)/256)*256;
    return p;
  };
  bf16_t* Xb   = alloc((size_t)BT*NC);
  bf16_t* Wqt  = alloc((size_t)3*NC*NC);
  bf16_t* Wot  = alloc((size_t)NC*NC);
  bf16_t* QKVb = alloc((size_t)BT*3*NC);
  bf16_t* Qb   = alloc((size_t)NB*NH*NT*HD);  // prescaled, [bh][t][d]
  bf16_t* Kb   = alloc((size_t)NB*NH*NT*HD);  // [bh][t][d]
  bf16_t* VT   = alloc((size_t)NB*NH*HD*NT);  // transposed [bh][d][t]
  bf16_t* Ob   = alloc((size_t)BT*NC);

  k_cvt_x<<<(BT*NC/4)/256, 256, 0, stream>>>(x, Xb, BT*NC);
  k_cvt_t<<<dim3(3*NC/32, NC/32), 256, 0, stream>>>(Wqkv, Wqt, NC, 3*NC);
  k_cvt_t<<<dim3(NC/32,   NC/32), 256, 0, stream>>>(Wout, Wot, NC, NC);
  k_gemm<false,true><<<dim3(3*NC/128, BT/128), 256, 0, stream>>>(Xb, Wqt, (void*)QKVb, nullptr, BT, 3*NC, NC);
  k_rope<<<(BT*1536)/256, 256, 0, stream>>>(QKVb, Qb, Kb, VT);
  float* attn = (float*)d_out + (size_t)BT*NC;
  k_attn<<<dim3(NB*NH, NT/64), 256, 0, stream>>>(Qb, Kb, VT, attn, Ob);
  k_gemm<true,false><<<dim3(NC/128, BT/128), 256, 0, stream>>>(Ob, Wot, d_out, bout, BT, NC, NC);
}